// Round 3
// baseline (599.480 us; speedup 1.0000x reference)
//
#include <hip/hip_runtime.h>
#include <float.h>
#include <math.h>

constexpr int NN  = 30000;   // nodes
constexpr int EE  = 300000;  // edges before self-loops
constexpr int GG  = 1024;    // graphs
constexpr int HID = 256;
constexpr int NH  = 8;       // heads
constexpr int EP  = EE + NN; // edges incl self-loops
constexpr int NP  = 30080;   // padded rows: 235 * 128

typedef short bf16x8 __attribute__((ext_vector_type(8)));
typedef float f32x4 __attribute__((ext_vector_type(4)));

__device__ __forceinline__ void gload_lds16(const void* g, void* l) {
    __builtin_amdgcn_global_load_lds(
        (const __attribute__((address_space(1))) unsigned int*)g,
        (__attribute__((address_space(3))) unsigned int*)l, 16, 0, 0);
}

__device__ __forceinline__ void f2hilo(float x, unsigned short& h, unsigned short& l) {
    unsigned u = __float_as_uint(x);
    h = (unsigned short)(u >> 16);                       // truncated hi
    float hv = __uint_as_float(u & 0xFFFF0000u);
    float r = x - hv;                                    // exact residual
    unsigned v = __float_as_uint(r);
    unsigned rnd = ((v >> 16) & 1u) + 0x7FFFu;           // RNE to bf16
    l = (unsigned short)((v + rnd) >> 16);
}

__device__ __forceinline__ float bf2f(unsigned short u) {
    return __uint_as_float(((unsigned)u) << 16);
}

// monotone float <-> uint map for deterministic atomicMax
__device__ __forceinline__ unsigned fmap(float x) {
    unsigned b = __float_as_uint(x);
    return (b & 0x80000000u) ? ~b : (b | 0x80000000u);
}
__device__ __forceinline__ float funmap(unsigned u) {
    return (u & 0x80000000u) ? __uint_as_float(u ^ 0x80000000u) : __uint_as_float(~u);
}

// ---------------- CSR build ----------------
__global__ void k_hist(const int* __restrict__ edst, int* __restrict__ cnt) {
    int i = blockIdx.x * blockDim.x + threadIdx.x;
    if (i >= EP) return;
    int d = (i < EE) ? edst[i] : (i - EE);
    atomicAdd(&cnt[d], 1);
}

__global__ void k_scan(const int* __restrict__ cnt, int* __restrict__ indptr) {
    __shared__ int wtot[16];
    __shared__ int carry_s;
    int tid = threadIdx.x;
    int lane = tid & 63, wid = tid >> 6;
    if (tid == 0) carry_s = 0;
    __syncthreads();
    for (int base = 0; base < NN; base += 1024) {
        int i = base + tid;
        int v = (i < NN) ? cnt[i] : 0;
        int incl = v;
        #pragma unroll
        for (int off = 1; off < 64; off <<= 1) {
            int t = __shfl_up(incl, off, 64);
            if (lane >= off) incl += t;
        }
        if (lane == 63) wtot[wid] = incl;
        __syncthreads();
        int wpre = 0;
        for (int w = 0; w < wid; ++w) wpre += wtot[w];
        int c = carry_s;
        if (i < NN) indptr[i] = c + wpre + incl - v;  // exclusive
        int tot = 0;
        for (int w = 0; w < 16; ++w) tot += wtot[w];
        __syncthreads();
        if (tid == 0) carry_s = c + tot;
        __syncthreads();
    }
    if (tid == 0) indptr[NN] = carry_s;
}

__global__ void k_fill(const int* __restrict__ esrc, const int* __restrict__ edst,
                       const int* __restrict__ indptr, int* __restrict__ cursor,
                       int* __restrict__ srcs) {
    int i = blockIdx.x * blockDim.x + threadIdx.x;
    if (i >= EP) return;
    int d, s;
    if (i < EE) { d = edst[i]; s = esrc[i]; } else { d = i - EE; s = i - EE; }
    int pos = indptr[d] + atomicAdd(&cursor[d], 1);
    srcs[pos] = s;
}

__global__ void k_sortseg(int* __restrict__ srcs, const int* __restrict__ indptr) {
    int node = blockIdx.x * blockDim.x + threadIdx.x;
    if (node >= NN) return;
    int b = indptr[node], e = indptr[node + 1];
    for (int i = b + 1; i < e; ++i) {
        int v = srcs[i];
        int j = i - 1;
        while (j >= b && srcs[j] > v) { srcs[j + 1] = srcs[j]; --j; }
        srcs[j + 1] = v;
    }
}

__global__ void k_starts(const int* __restrict__ batch, int* __restrict__ starts) {
    int i = blockIdx.x * blockDim.x + threadIdx.x;
    if (i >= NN) return;
    int b = batch[i];
    if (i == 0 || batch[i - 1] != b) starts[b] = i;
    if (i == NN - 1) starts[GG] = NN;
}

// ---------------- weight split fp32 -> bf16 hi/lo ----------------
__global__ void k_wconv(const float* __restrict__ W1, const float* __restrict__ W2,
                        const float* __restrict__ W3, const float* __restrict__ W4,
                        const float* __restrict__ W5,
                        unsigned short* __restrict__ Whi, unsigned short* __restrict__ Wlo) {
    int i = blockIdx.x * blockDim.x + threadIdx.x;  // 0..65535
    int l = blockIdx.y;
    const float* W = (l == 0) ? W1 : (l == 1) ? W2 : (l == 2) ? W3 : (l == 3) ? W4 : W5;
    unsigned short h, lo;
    f2hilo(W[i], h, lo);
    Whi[(size_t)l * 65536 + i] = h;
    Wlo[(size_t)l * 65536 + i] = lo;
}

// ---------------- embedding with max_norm=1 -> hi/lo ----------------
__global__ void k_embed(const int* __restrict__ ids, const float* __restrict__ emb,
                        unsigned short* __restrict__ Phi, unsigned short* __restrict__ Plo) {
    int w = (blockIdx.x * blockDim.x + threadIdx.x) >> 6;
    if (w >= NN) return;
    int lane = threadIdx.x & 63;
    const float4 v = *(const float4*)(emb + (size_t)ids[w] * HID + lane * 4);
    float ss = v.x * v.x + v.y * v.y + v.z * v.z + v.w * v.w;
    #pragma unroll
    for (int off = 32; off >= 1; off >>= 1) ss += __shfl_xor(ss, off, 64);
    float nrm = sqrtf(ss);
    float sc = fminf(1.0f, 1.0f / (nrm + 1e-12f));
    float o[4] = {v.x * sc, v.y * sc, v.z * sc, v.w * sc};
    ushort4 hv, lv;
    f2hilo(o[0], hv.x, lv.x); f2hilo(o[1], hv.y, lv.y);
    f2hilo(o[2], hv.z, lv.z); f2hilo(o[3], hv.w, lv.w);
    *(ushort4*)(Phi + (size_t)w * HID + lane * 4) = hv;
    *(ushort4*)(Plo + (size_t)w * HID + lane * 4) = lv;
}

// ---------------- split-bf16 MFMA GEMM + fused attention-logit epilogue ----------------
// O[M,256] = (hi+lo)X @ (hi+lo)W^T ; es/ed[row][head] = <O-row slice, a_src/a_dst>
__global__ __launch_bounds__(256) void k_gemm(const unsigned short* __restrict__ Ahi,
                                              const unsigned short* __restrict__ Alo,
                                              const unsigned short* __restrict__ Bhi,
                                              const unsigned short* __restrict__ Blo,
                                              const float* __restrict__ a_src,
                                              const float* __restrict__ a_dst,
                                              float* __restrict__ O,
                                              float* __restrict__ es,
                                              float* __restrict__ ed, int M) {
    __shared__ unsigned short lds[4][128 * 64];  // Ahi, Alo, Bhi, Blo: 16KB each
    const int tid = threadIdx.x;
    const int m0 = blockIdx.x * 128;
    const int n0 = blockIdx.y * 128;
    const int wid = tid >> 6, lane = tid & 63;
    const int wm = wid >> 1, wn = wid & 1;
    const int r16 = lane & 15, kq = lane >> 4;

    f32x4 acc[4][4];
    #pragma unroll
    for (int i = 0; i < 4; ++i)
        #pragma unroll
        for (int j = 0; j < 4; ++j) acc[i][j] = (f32x4){0.f, 0.f, 0.f, 0.f};

    for (int kt = 0; kt < 4; ++kt) {
        const int kk = kt * 64;
        #pragma unroll
        for (int rnd = 0; rnd < 4; ++rnd) {
            int q = rnd * 256 + tid;
            int row = q >> 3, c = q & 7;
            int sc = c ^ (row & 7);
            size_t goffA = (size_t)(m0 + row) * HID + kk + sc * 8;
            size_t goffB = (size_t)(n0 + row) * HID + kk + sc * 8;
            gload_lds16(Ahi + goffA, &lds[0][q * 8]);
            gload_lds16(Alo + goffA, &lds[1][q * 8]);
            gload_lds16(Bhi + goffB, &lds[2][q * 8]);
            gload_lds16(Blo + goffB, &lds[3][q * 8]);
        }
        __syncthreads();
        #pragma unroll
        for (int ks = 0; ks < 2; ++ks) {
            bf16x8 ah[4], al[4], bh[4], bl[4];
            #pragma unroll
            for (int f = 0; f < 4; ++f) {
                int rowa = wm * 64 + f * 16 + r16;
                int ca = (ks * 4 + kq) ^ (rowa & 7);
                int offa = rowa * 64 + ca * 8;
                ah[f] = *(const bf16x8*)&lds[0][offa];
                al[f] = *(const bf16x8*)&lds[1][offa];
                int rowb = wn * 64 + f * 16 + r16;
                int cb = (ks * 4 + kq) ^ (rowb & 7);
                int offb = rowb * 64 + cb * 8;
                bh[f] = *(const bf16x8*)&lds[2][offb];
                bl[f] = *(const bf16x8*)&lds[3][offb];
            }
            #pragma unroll
            for (int mi = 0; mi < 4; ++mi)
                #pragma unroll
                for (int ni = 0; ni < 4; ++ni) {
                    acc[mi][ni] = __builtin_amdgcn_mfma_f32_16x16x32_bf16(ah[mi], bh[ni], acc[mi][ni], 0, 0, 0);
                    acc[mi][ni] = __builtin_amdgcn_mfma_f32_16x16x32_bf16(ah[mi], bl[ni], acc[mi][ni], 0, 0, 0);
                    acc[mi][ni] = __builtin_amdgcn_mfma_f32_16x16x32_bf16(al[mi], bh[ni], acc[mi][ni], 0, 0, 0);
                }
        }
        __syncthreads();
    }
    // this wave's 64-col quadrant holds exactly 2 heads (head = col>>5)
    const int headA = (n0 >> 5) + wn * 2;
    const float asA0 = a_src[headA * 32 + r16],      asA1 = a_src[headA * 32 + 16 + r16];
    const float asB0 = a_src[headA * 32 + 32 + r16], asB1 = a_src[headA * 32 + 48 + r16];
    const float adA0 = a_dst[headA * 32 + r16],      adA1 = a_dst[headA * 32 + 16 + r16];
    const float adB0 = a_dst[headA * 32 + 32 + r16], adB1 = a_dst[headA * 32 + 48 + r16];
    // C/D layout: col = lane&15, row = (lane>>4)*4 + reg  [m89-verified]
    #pragma unroll
    for (int mi = 0; mi < 4; ++mi) {
        #pragma unroll
        for (int q = 0; q < 4; ++q) {
            int row = m0 + wm * 64 + mi * 16 + kq * 4 + q;
            float ps0 = acc[mi][0][q] * asA0 + acc[mi][1][q] * asA1;
            float ps1 = acc[mi][2][q] * asB0 + acc[mi][3][q] * asB1;
            float pd0 = acc[mi][0][q] * adA0 + acc[mi][1][q] * adA1;
            float pd1 = acc[mi][2][q] * adB0 + acc[mi][3][q] * adB1;
            #pragma unroll
            for (int off = 1; off < 16; off <<= 1) {
                ps0 += __shfl_xor(ps0, off, 16);
                ps1 += __shfl_xor(ps1, off, 16);
                pd0 += __shfl_xor(pd0, off, 16);
                pd1 += __shfl_xor(pd1, off, 16);
            }
            if (row < M) {
                #pragma unroll
                for (int ni = 0; ni < 4; ++ni)
                    O[(size_t)row * HID + n0 + wn * 64 + ni * 16 + r16] = acc[mi][ni][q];
                if (r16 == 0) {
                    es[row * NH + headA]     = ps0;
                    es[row * NH + headA + 1] = ps1;
                    ed[row * NH + headA]     = pd0;
                    ed[row * NH + headA + 1] = pd1;
                }
            }
        }
    }
}

// ---------------- edge-parallel logits + deterministic segment max ----------------
__global__ void k_edge(const int* __restrict__ eidx, const float* __restrict__ es,
                       const float* __restrict__ ed, float* __restrict__ elog,
                       unsigned* __restrict__ mU) {
    int t = blockIdx.x * blockDim.x + threadIdx.x;
    if (t >= EP * NH) return;
    int j = t >> 3, h = t & 7;
    int s, d;
    if (j < EE) { s = eidx[j]; d = eidx[EE + j]; } else { s = j - EE; d = s; }
    float e = es[s * NH + h] + ed[d * NH + h];
    e = (e > 0.f) ? e : 0.2f * e;
    elog[t] = e;
    atomicMax(&mU[d * NH + h], fmap(e));
}

// ---------------- single-pass weighted aggregate + bias + relu -> hi/lo ----------------
__global__ __launch_bounds__(256) void k_aggregate(const float* __restrict__ H,
                                                   const float* __restrict__ elog,
                                                   const unsigned* __restrict__ mU,
                                                   const int* __restrict__ indptr,
                                                   const int* __restrict__ srcs,
                                                   const float* __restrict__ bias,
                                                   unsigned short* __restrict__ Phi,
                                                   unsigned short* __restrict__ Plo) {
    int node = (blockIdx.x * blockDim.x + threadIdx.x) >> 6;
    if (node >= NN) return;
    int lane = threadIdx.x & 63;
    int head = lane >> 3;
    int b0 = indptr[node], e0 = indptr[node + 1];
    float m = funmap(mU[node * NH + head]);
    float4 a0 = {0.f, 0.f, 0.f, 0.f}, a1 = a0, a2 = a0, a3 = a0;
    float s0 = 0.f, s1 = 0.f, s2 = 0.f, s3 = 0.f;
    int j = b0;
    for (; j + 3 < e0; j += 4) {
        int x0 = srcs[j], x1 = srcs[j + 1], x2 = srcs[j + 2], x3 = srcs[j + 3];
        float ev0 = elog[(size_t)(j + 0) * NH + head];
        float ev1 = elog[(size_t)(j + 1) * NH + head];
        float ev2 = elog[(size_t)(j + 2) * NH + head];
        float ev3 = elog[(size_t)(j + 3) * NH + head];
        float4 h0 = *(const float4*)(H + (size_t)x0 * HID + lane * 4);
        float4 h1 = *(const float4*)(H + (size_t)x1 * HID + lane * 4);
        float4 h2 = *(const float4*)(H + (size_t)x2 * HID + lane * 4);
        float4 h3 = *(const float4*)(H + (size_t)x3 * HID + lane * 4);
        float w0 = expf(ev0 - m), w1 = expf(ev1 - m);
        float w2 = expf(ev2 - m), w3 = expf(ev3 - m);
        s0 += w0; s1 += w1; s2 += w2; s3 += w3;
        a0.x = fmaf(w0, h0.x, a0.x); a0.y = fmaf(w0, h0.y, a0.y);
        a0.z = fmaf(w0, h0.z, a0.z); a0.w = fmaf(w0, h0.w, a0.w);
        a1.x = fmaf(w1, h1.x, a1.x); a1.y = fmaf(w1, h1.y, a1.y);
        a1.z = fmaf(w1, h1.z, a1.z); a1.w = fmaf(w1, h1.w, a1.w);
        a2.x = fmaf(w2, h2.x, a2.x); a2.y = fmaf(w2, h2.y, a2.y);
        a2.z = fmaf(w2, h2.z, a2.z); a2.w = fmaf(w2, h2.w, a2.w);
        a3.x = fmaf(w3, h3.x, a3.x); a3.y = fmaf(w3, h3.y, a3.y);
        a3.z = fmaf(w3, h3.z, a3.z); a3.w = fmaf(w3, h3.w, a3.w);
    }
    for (; j < e0; ++j) {
        int x0 = srcs[j];
        float ev = elog[(size_t)j * NH + head];
        float4 h0 = *(const float4*)(H + (size_t)x0 * HID + lane * 4);
        float w0 = expf(ev - m);
        s0 += w0;
        a0.x = fmaf(w0, h0.x, a0.x); a0.y = fmaf(w0, h0.y, a0.y);
        a0.z = fmaf(w0, h0.z, a0.z); a0.w = fmaf(w0, h0.w, a0.w);
    }
    float sum = (s0 + s1) + (s2 + s3);
    float ax = (a0.x + a1.x) + (a2.x + a3.x);
    float ay = (a0.y + a1.y) + (a2.y + a3.y);
    float az = (a0.z + a1.z) + (a2.z + a3.z);
    float aw = (a0.w + a1.w) + (a2.w + a3.w);
    float inv = 1.f / (sum + 1e-16f);
    float4 bv = *(const float4*)(bias + lane * 4);
    float o[4];
    o[0] = fmaxf(fmaf(ax, inv, bv.x), 0.f);
    o[1] = fmaxf(fmaf(ay, inv, bv.y), 0.f);
    o[2] = fmaxf(fmaf(az, inv, bv.z), 0.f);
    o[3] = fmaxf(fmaf(aw, inv, bv.w), 0.f);
    ushort4 hv, lv;
    f2hilo(o[0], hv.x, lv.x); f2hilo(o[1], hv.y, lv.y);
    f2hilo(o[2], hv.z, lv.z); f2hilo(o[3], hv.w, lv.w);
    *(ushort4*)(Phi + (size_t)node * HID + lane * 4) = hv;
    *(ushort4*)(Plo + (size_t)node * HID + lane * 4) = lv;
}

// ---------------- per-graph max pool + linear head ----------------
__global__ void k_pool(const unsigned short* __restrict__ Phi,
                       const unsigned short* __restrict__ Plo,
                       const int* __restrict__ starts,
                       const float* __restrict__ fw, const float* __restrict__ fb,
                       float* __restrict__ out) {
    int g = (blockIdx.x * blockDim.x + threadIdx.x) >> 6;
    if (g >= GG) return;
    int lane = threadIdx.x & 63;
    int s = starts[g], e = starts[g + 1];
    float mx0 = -FLT_MAX, mx1 = -FLT_MAX, mx2 = -FLT_MAX, mx3 = -FLT_MAX;
    for (int n = s; n < e; ++n) {
        ushort4 hv = *(const ushort4*)(Phi + (size_t)n * HID + lane * 4);
        ushort4 lv = *(const ushort4*)(Plo + (size_t)n * HID + lane * 4);
        mx0 = fmaxf(mx0, bf2f(hv.x) + bf2f(lv.x));
        mx1 = fmaxf(mx1, bf2f(hv.y) + bf2f(lv.y));
        mx2 = fmaxf(mx2, bf2f(hv.z) + bf2f(lv.z));
        mx3 = fmaxf(mx3, bf2f(hv.w) + bf2f(lv.w));
    }
    float4 w = *(const float4*)(fw + lane * 4);
    float t = mx0 * w.x + mx1 * w.y + mx2 * w.z + mx3 * w.w;
    #pragma unroll
    for (int off = 32; off >= 1; off >>= 1) t += __shfl_xor(t, off, 64);
    if (lane == 0) out[g] = t + fb[0];
}

// ---------------- launcher ----------------
extern "C" void kernel_launch(void* const* d_in, const int* in_sizes, int n_in,
                              void* d_out, int out_size, void* d_ws, size_t ws_size,
                              hipStream_t stream) {
    const int* x_ids = (const int*)d_in[0];
    const int* eidx  = (const int*)d_in[1];
    const int* batch = (const int*)d_in[2];
    const float* emb = (const float*)d_in[3];
    const float* fw  = (const float*)d_in[4];
    const float* fb  = (const float*)d_in[5];
    const float* Wl[5], *asl[5], *adl[5], *bl[5];
    for (int l = 0; l < 5; ++l) {
        Wl[l]  = (const float*)d_in[6 + 4 * l];
        asl[l] = (const float*)d_in[7 + 4 * l];
        adl[l] = (const float*)d_in[8 + 4 * l];
        bl[l]  = (const float*)d_in[9 + 4 * l];
    }

    char* ws = (char*)d_ws;
    size_t off = 0;
    auto alloc = [&](size_t bytes) {
        void* p = ws + off;
        off = (off + bytes + 255) & ~(size_t)255;
        return p;
    };
    unsigned short* Phi = (unsigned short*)alloc((size_t)NP * HID * 2);
    unsigned short* Plo = (unsigned short*)alloc((size_t)NP * HID * 2);
    float* Q    = (float*)alloc((size_t)NN * HID * 4);
    unsigned short* Whi = (unsigned short*)alloc((size_t)5 * HID * HID * 2);
    unsigned short* Wlo = (unsigned short*)alloc((size_t)5 * HID * HID * 2);
    float* es   = (float*)alloc((size_t)NN * NH * 4);
    float* ed   = (float*)alloc((size_t)NN * NH * 4);
    float* elog = (float*)alloc((size_t)EP * NH * 4);
    unsigned* mU = (unsigned*)alloc((size_t)5 * NN * NH * 4);
    int* cnt    = (int*)alloc((size_t)NN * 4);
    int* cursor = (int*)alloc((size_t)NN * 4);
    int* indptr = (int*)alloc((size_t)(NN + 1) * 4);
    int* srcs   = (int*)alloc((size_t)EP * 4);
    int* starts = (int*)alloc((size_t)(GG + 1) * 4);
    (void)ws_size; (void)in_sizes; (void)n_in; (void)out_size;

    hipMemsetAsync(cnt, 0, (size_t)NN * 4, stream);
    hipMemsetAsync(cursor, 0, (size_t)NN * 4, stream);
    hipMemsetAsync(mU, 0, (size_t)5 * NN * NH * 4, stream);  // 0 < fmap(any float)

    k_hist<<<(EP + 255) / 256, 256, 0, stream>>>(eidx + EE, cnt);
    k_scan<<<1, 1024, 0, stream>>>(cnt, indptr);
    k_fill<<<(EP + 255) / 256, 256, 0, stream>>>(eidx, eidx + EE, indptr, cursor, srcs);
    k_sortseg<<<(NN + 255) / 256, 256, 0, stream>>>(srcs, indptr);
    k_starts<<<(NN + 255) / 256, 256, 0, stream>>>(batch, starts);
    k_wconv<<<dim3(HID * HID / 256, 5), 256, 0, stream>>>(Wl[0], Wl[1], Wl[2], Wl[3], Wl[4], Whi, Wlo);
    k_embed<<<NN / 4, 256, 0, stream>>>(x_ids, emb, Phi, Plo);

    for (int l = 0; l < 5; ++l) {
        unsigned* mUl = mU + (size_t)l * NN * NH;
        dim3 gg(NP / 128, HID / 128);
        k_gemm<<<gg, 256, 0, stream>>>(Phi, Plo, Whi + (size_t)l * HID * HID,
                                       Wlo + (size_t)l * HID * HID,
                                       asl[l], adl[l], Q, es, ed, NN);
        k_edge<<<(EP * NH + 255) / 256, 256, 0, stream>>>(eidx, es, ed, elog, mUl);
        k_aggregate<<<NN / 4, 256, 0, stream>>>(Q, elog, mUl, indptr, srcs, bl[l], Phi, Plo);
    }
    k_pool<<<GG / 4, 256, 0, stream>>>(Phi, Plo, starts, fw, fb, (float*)d_out);
}